// Round 13
// baseline (19441.269 us; speedup 1.0000x reference)
//
#include <hip/hip_runtime.h>

// ContinuousGRULayer round 13: r12 (i8 weights, i8 h, x-part precompute) with
// the gate-split replaced by a K-SPLIT PAIR layout -> 2 barriers/eval (was 3).
//   Wave w: lanes 0-31 = K-half 0, lanes 32-63 = K-half 1 of neurons
//   j = w*32+lane%32. Each thread does z,r,g partials over its K-half;
//   __shfl_xor(.,32) completes sums in-wave (no barrier); both lanes compute
//   gates/RK4 redundantly (bit-identical). gpart exchange + barrier deleted.
//   Byte economics identical to r11/r12: 8 opaque reg slices, 9 LDS reads,
//   31 streamed uint4 per thread per eval.

namespace {
constexpr int kB = 128, kT = 512, kF = 128, kH = 512, kFH = 640;
// uint4-unit offsets in d_ws
constexpr int QZ4 = 0, QR4 = 16384, QG4 = 32768;        // i8 recurrent, 32 slices/gate
constexpr int WXZ4 = 49152, WXR4 = 57344, WXG4 = 65536; // f16 x-part, 16 slices/gate
constexpr size_t CS_OFF = (size_t)73728 * 16;           // 3*512 f32 scales
constexpr size_t AXP_OFF = 1310720;                     // f16 x-part results
constexpr size_t AXP_BYTES = (size_t)kB * kT * 3 * kH * 2;  // 201 MB
constexpr float HSCL = 100.0f;                          // h scale (clip 1.27)
}  // namespace

typedef _Float16 h2_t __attribute__((ext_vector_type(2)));

__device__ __forceinline__ unsigned short f2h(float f) {
  return __builtin_bit_cast(unsigned short, (_Float16)f);
}
__device__ __forceinline__ unsigned pack2h(float a, float b) {
  return (unsigned)f2h(a) | ((unsigned)f2h(b) << 16);
}
__device__ __forceinline__ float h2f(unsigned short u) {
  return (float)__builtin_bit_cast(_Float16, u);
}
__device__ __forceinline__ float dot2(unsigned w, unsigned h, float acc) {
  return __builtin_amdgcn_fdot2(__builtin_bit_cast(h2_t, w),
                                __builtin_bit_cast(h2_t, h), acc, false);
}
__device__ __forceinline__ float dot2x4(uint4 w, uint4 h, float acc) {
  acc = dot2(w.x, h.x, acc); acc = dot2(w.y, h.y, acc);
  acc = dot2(w.z, h.z, acc); acc = dot2(w.w, h.w, acc);
  return acc;
}
__device__ __forceinline__ uint4 pk8(const float* s) {
  const float4 a = *(const float4*)s;
  const float4 b = *(const float4*)(s + 4);
  uint4 o;
  o.x = pack2h(a.x, a.y); o.y = pack2h(a.z, a.w);
  o.z = pack2h(b.x, b.y); o.w = pack2h(b.z, b.w);
  return o;
}
__device__ __forceinline__ int sd4(unsigned a, unsigned b, int acc) {
  return __builtin_amdgcn_sdot4((int)a, (int)b, acc, false);
}
__device__ __forceinline__ void dslice(const uint4 w, const unsigned* hq,
                                       int p, int& acc) {
  acc = sd4(w.x, hq[4 * p + 0], acc);
  acc = sd4(w.y, hq[4 * p + 1], acc);
  acc = sd4(w.z, hq[4 * p + 2], acc);
  acc = sd4(w.w, hq[4 * p + 3], acc);
}

#define DECL_OPQ(v, ptr, s)                                          \
  uint4 v = (ptr)[(s) * kH];                                         \
  asm volatile("" : "+v"(v.x), "+v"(v.y), "+v"(v.z), "+v"(v.w))

// ---- pre-pack: i8 recurrent (per-row scale) + f16 x-part + scales ----
__global__ void quant_weights(const float* __restrict__ Wz,
                              const float* __restrict__ Wr,
                              const float* __restrict__ Wg,
                              void* __restrict__ ws) {
  const int bx = blockIdx.x;            // 0..1535 = gate*512 + j
  const int gate = bx >> 9, j = bx & 511;
  const float* W = (gate == 0) ? Wz : (gate == 1) ? Wr : Wg;
  const float* row = W + (size_t)j * kFH;
  const int lane = threadIdx.x;         // 0..63, owns recurrent cols 8l..8l+7
  uint4* ws4 = (uint4*)ws;

  const float* src = row + kF + lane * 8;
  float v[8]; float m = 0.f;
#pragma unroll
  for (int i = 0; i < 8; ++i) { v[i] = src[i]; m = fmaxf(m, fabsf(v[i])); }
#pragma unroll
  for (int off = 32; off; off >>= 1) m = fmaxf(m, __shfl_xor(m, off));
  const float inv = 127.f / m;
  unsigned u0 = 0, u1 = 0;
#pragma unroll
  for (int i = 0; i < 4; ++i) {
    int q = __float2int_rn(v[i] * inv); q = max(-127, min(127, q));
    u0 |= ((unsigned)(q & 255)) << (8 * i);
  }
#pragma unroll
  for (int i = 0; i < 4; ++i) {
    int q = __float2int_rn(v[4 + i] * inv); q = max(-127, min(127, q));
    u1 |= ((unsigned)(q & 255)) << (8 * i);
  }
  const int p = lane >> 1, sub = lane & 1;
  const int qbase = (gate == 0) ? QZ4 : (gate == 1) ? QR4 : QG4;
  *(uint2*)((char*)ws + ((size_t)(qbase + p * kH + j)) * 16 + sub * 8) =
      make_uint2(u0, u1);
  if (lane < 16) {
    const int xbase = (gate == 0) ? WXZ4 : (gate == 1) ? WXR4 : WXG4;
    ws4[xbase + lane * kH + j] = pk8(row + lane * 8);
  }
  if (lane == 0)
    ((float*)((char*)ws + CS_OFF))[gate * 512 + j] = m / (127.f * HSCL);
}

// ---- x-part precompute: ax[b][t][gate][j] = b_gate[j] + Wx_gate[j].x_t ----
__global__ __launch_bounds__(512) void xpart_pre(
    const float* __restrict__ x, const float* __restrict__ bz,
    const float* __restrict__ br, const float* __restrict__ bg,
    const uint4* __restrict__ ws, unsigned short* __restrict__ axp) {
  __shared__ unsigned xt[8][64];        // 8 timesteps x 128 f16
  const int bx = blockIdx.x;            // 0..8191
  const int b = bx >> 6;
  const int t0 = (bx & 63) * 8;
  const int tid = threadIdx.x;          // 0..511 = j
  {
    const int m = tid >> 6, c = tid & 63;
    const float2 xv =
        *(const float2*)(x + ((size_t)b * kT + t0 + m) * kF + 2 * c);
    xt[m][c] = pack2h(xv.x, xv.y);
  }
  __syncthreads();
#pragma unroll
  for (int gate = 0; gate < 3; ++gate) {
    const uint4* wx =
        ws + ((gate == 0) ? WXZ4 : (gate == 1) ? WXR4 : WXG4) + tid;
    const float bv = ((gate == 0) ? bz : (gate == 1) ? br : bg)[tid];
    float acc[8];
#pragma unroll
    for (int m = 0; m < 8; ++m) acc[m] = bv;
#pragma unroll
    for (int p = 0; p < 16; ++p) {
      const uint4 w = wx[p * kH];
#pragma unroll
      for (int m = 0; m < 8; ++m)
        acc[m] = dot2x4(w, ((const uint4*)xt[m])[p], acc[m]);
    }
#pragma unroll
    for (int m = 0; m < 8; ++m)
      axp[(((size_t)b * kT + t0 + m) * 3 + gate) * kH + tid] = f2h(acc[m]);
  }
}

template <int XPRE>
__global__ __launch_bounds__(1024, 4) void cgru_i8p(
    const float* __restrict__ x, const float* __restrict__ td,
    const float* __restrict__ bz, const float* __restrict__ br,
    const float* __restrict__ bg, const uint4* __restrict__ ws,
    const unsigned short* __restrict__ axp, float* __restrict__ out) {
  __shared__ uint4 WLz[2][3][kH];      // z slices kh*16+{4..6}   49,152 B
  __shared__ uint4 WLr[2][3][kH];      // r slices kh*16+{4..6}   49,152 B
  __shared__ uint4 WLg[2][3][kH];      // g slices kh*16+{0..2}   49,152 B
  __shared__ unsigned hq[kH / 4];      // h, i8 plane (512 B)
  __shared__ unsigned rq[kH / 4];      // r*h, i8 plane
  __shared__ unsigned xpk[kF / 2];     // x_t f16 (fallback mode only)

  const int b = blockIdx.x;
  const int tid = threadIdx.x;
  const int kh = (tid >> 5) & 1;                     // K-half
  const int j = ((tid >> 6) << 5) | (tid & 31);      // neuron 0..511
  const int sb = kh << 4;                            // slice base

  const uint4* __restrict__ wz = ws + QZ4 + j;
  const uint4* __restrict__ wr = ws + QR4 + j;
  const uint4* __restrict__ wg = ws + QG4 + j;
  const uint4* __restrict__ wxz = ws + WXZ4 + j;
  const uint4* __restrict__ wxr = ws + WXR4 + j;
  const uint4* __restrict__ wxg = ws + WXG4 + j;
  const float* cs = (const float*)((const char*)ws + CS_OFF);
  const float csz = cs[j], csr = cs[512 + j], csg = cs[1024 + j];

  // ---- reg-resident slices (asm-opaque): z,r slices sb+0..3 (32 VGPR) ----
  DECL_OPQ(z0, wz, sb + 0); DECL_OPQ(z1, wz, sb + 1);
  DECL_OPQ(z2, wz, sb + 2); DECL_OPQ(z3, wz, sb + 3);
  DECL_OPQ(r0, wr, sb + 0); DECL_OPQ(r1, wr, sb + 1);
  DECL_OPQ(r2, wr, sb + 2); DECL_OPQ(r3, wr, sb + 3);
  // ---- LDS-resident slices ----
#pragma unroll
  for (int q = 0; q < 3; ++q) {
    WLz[kh][q][j] = wz[(sb + 4 + q) * kH];
    WLr[kh][q][j] = wr[(sb + 4 + q) * kH];
    WLg[kh][q][j] = wg[(sb + q) * kH];
  }

  const float bzv = bz[j], brv = br[j], bgv = bg[j];
  float hb = 0.f, hs = 0.f, kacc = 0.f;
  if (tid < kH / 4) hq[tid] = 0;       // h = 0
  __syncthreads();                     // hq init + LDS weights visible

  for (int t = 0; t < kT; ++t) {
    float axz, axr, axg;
    if constexpr (XPRE) {
      const size_t bt3 = ((size_t)b * kT + t) * 3;
      axz = h2f(axp[(bt3 + 0) * kH + j]);
      axr = h2f(axp[(bt3 + 1) * kH + j]);
      axg = h2f(axp[(bt3 + 2) * kH + j]);
    } else {
      if (tid < kF / 2) {
        const float2 xv =
            *(const float2*)(x + ((size_t)b * kT + t) * kF + 2 * tid);
        xpk[tid] = pack2h(xv.x, xv.y);
      }
      __syncthreads();
      const uint4* xp4 = (const uint4*)xpk;
      axz = bzv; axr = brv; axg = bgv;
#pragma unroll 4
      for (int p = 0; p < 16; ++p) {
        const uint4 xv = xp4[p];
        axz = dot2x4(wxz[p * kH], xv, axz);
        axr = dot2x4(wxr[p * kH], xv, axr);
        axg = dot2x4(wxg[p * kH], xv, axg);
      }
      __syncthreads();   // xpk reads done before next t overwrites
    }
    const float dtv = fminf(td[(size_t)b * kT + t], 1.0f) * 0.5f;

    for (int e = 0; e < 8; ++e) {   // 2 ODE steps x 4 RK4 stages
      const int s = e & 3;
      // ---- z,r partials over own K-half: 4 reg + 3 LDS + 9 streamed ----
      int za = 0, ra = 0;
      dslice(z0, hq, sb + 0, za); dslice(r0, hq, sb + 0, ra);
      dslice(z1, hq, sb + 1, za); dslice(r1, hq, sb + 1, ra);
      dslice(z2, hq, sb + 2, za); dslice(r2, hq, sb + 2, ra);
      dslice(z3, hq, sb + 3, za); dslice(r3, hq, sb + 3, ra);
#pragma unroll
      for (int q = 0; q < 3; ++q) {
        dslice(WLz[kh][q][j], hq, sb + 4 + q, za);
        dslice(WLr[kh][q][j], hq, sb + 4 + q, ra);
      }
#pragma unroll 3
      for (int p = sb + 7; p < sb + 16; ++p) {
        dslice(wz[p * kH], hq, p, za);
        dslice(wr[p * kH], hq, p, ra);
      }
      za += __shfl_xor(za, 32);       // complete K-sum in-wave
      ra += __shfl_xor(ra, 32);
      const float aZ = axz + csz * (float)za;
      const float aR = axr + csr * (float)ra;
      const float zv = 1.0f / (1.0f + __expf(-aZ));
      const float rv = 1.0f / (1.0f + __expf(-aR));
      const float rh = rv * hs;
      if (kh == 0) {
        int q = __float2int_rn(fminf(fmaxf(rh, -1.27f), 1.27f) * HSCL);
        ((char*)rq)[j] = (char)q;
      }
      __syncthreads();   // #1: rq visible; hq reads done

      // ---- g partial over own K-half of rq: 3 LDS + 13 streamed ----
      int ga = 0;
#pragma unroll
      for (int q = 0; q < 3; ++q)
        dslice(WLg[kh][q][j], rq, sb + q, ga);
#pragma unroll 4
      for (int p = sb + 3; p < sb + 16; ++p)
        dslice(wg[p * kH], rq, p, ga);
      ga += __shfl_xor(ga, 32);
      const float g = tanhf(axg + csg * (float)ga);

      // ---- RK4 commit (redundant in both lanes, bit-identical) ----
      const float kk = (1.0f - zv) * (g - hs);
      kacc = (s == 0) ? kk : kacc + ((s == 3) ? 1.0f : 2.0f) * kk;
      float nxt;
      if (s < 3) {
        nxt = fmaf((s == 2 ? 1.0f : 0.5f) * dtv, kk, hb);
      } else {
        hb = fmaf(dtv * (1.0f / 6.0f), kacc, hb);
        nxt = hb;
      }
      hs = nxt;
      if (kh == 0) {
        int q = __float2int_rn(fminf(fmaxf(nxt, -1.27f), 1.27f) * HSCL);
        ((char*)hq)[j] = (char)q;
      }
      __syncthreads();   // #2: new h visible; rq reads done
    }

    if (kh == 0) out[((size_t)b * kT + t) * kH + j] = hb;  // coalesced
  }
}

extern "C" void kernel_launch(void* const* d_in, const int* in_sizes, int n_in,
                              void* d_out, int out_size, void* d_ws, size_t ws_size,
                              hipStream_t stream) {
  const float* x  = (const float*)d_in[0];
  const float* td = (const float*)d_in[1];
  const float* Wz = (const float*)d_in[2];
  const float* bz = (const float*)d_in[3];
  const float* Wr = (const float*)d_in[4];
  const float* br = (const float*)d_in[5];
  const float* Wg = (const float*)d_in[6];
  const float* bg = (const float*)d_in[7];
  float* out = (float*)d_out;

  quant_weights<<<3 * kH, 64, 0, stream>>>(Wz, Wr, Wg, d_ws);

  unsigned short* axp = (unsigned short*)((char*)d_ws + AXP_OFF);
  if (ws_size >= AXP_OFF + AXP_BYTES) {
    xpart_pre<<<kB * (kT / 8), 512, 0, stream>>>(
        x, bz, br, bg, (const uint4*)d_ws, axp);
    cgru_i8p<1><<<kB, 1024, 0, stream>>>(
        x, td, bz, br, bg, (const uint4*)d_ws, axp, out);
  } else {
    cgru_i8p<0><<<kB, 1024, 0, stream>>>(
        x, td, bz, br, bg, (const uint4*)d_ws, axp, out);
  }
}

// Round 15
// 19358.511 us; speedup vs baseline: 1.0043x; 1.0043x over previous
//
#include <hip/hip_runtime.h>

// ContinuousGRULayer round 15: REVERT to the round-12 WIN (19.35 ms).
//   i8 recurrent weights (per-row scale) streamed, single-level i8 h
//   (scale 100, clip 1.27), gate-split 1024-thread shell, 3 barriers/eval,
//   x-part precomputed for all (b,t) into d_ws (f16), residency 8 opaque reg
//   + 9 LDS slice arrays.
// Round 14 mapped the i4 frontier: all-streamed-i4 -> absmax 0.0244 > 0.015.
// i8 is the precision floor; 508 KB/eval streamed is the byte floor; r12 runs
// at ~85% of the per-CU L1-fill wall. This is the terminal structure.

namespace {
constexpr int kB = 128, kT = 512, kF = 128, kH = 512, kFH = 640;
// uint4-unit offsets in d_ws
constexpr int QZ4 = 0, QR4 = 16384, QG4 = 32768;        // i8 recurrent, 32 slices/gate
constexpr int WXZ4 = 49152, WXR4 = 57344, WXG4 = 65536; // f16 x-part, 16 slices/gate
constexpr size_t CS_OFF = (size_t)73728 * 16;           // 3*512 f32 scales
constexpr size_t AXP_OFF = 1310720;                     // f16 x-part results
constexpr size_t AXP_BYTES = (size_t)kB * kT * 3 * kH * 2;  // 201 MB
constexpr float HSCL = 100.0f;                          // h scale (clip 1.27)
}  // namespace

typedef _Float16 h2_t __attribute__((ext_vector_type(2)));

__device__ __forceinline__ unsigned short f2h(float f) {
  return __builtin_bit_cast(unsigned short, (_Float16)f);
}
__device__ __forceinline__ unsigned pack2h(float a, float b) {
  return (unsigned)f2h(a) | ((unsigned)f2h(b) << 16);
}
__device__ __forceinline__ float h2f(unsigned short u) {
  return (float)__builtin_bit_cast(_Float16, u);
}
__device__ __forceinline__ float dot2(unsigned w, unsigned h, float acc) {
  return __builtin_amdgcn_fdot2(__builtin_bit_cast(h2_t, w),
                                __builtin_bit_cast(h2_t, h), acc, false);
}
__device__ __forceinline__ float dot2x4(uint4 w, uint4 h, float acc) {
  acc = dot2(w.x, h.x, acc); acc = dot2(w.y, h.y, acc);
  acc = dot2(w.z, h.z, acc); acc = dot2(w.w, h.w, acc);
  return acc;
}
__device__ __forceinline__ uint4 pk8(const float* s) {
  const float4 a = *(const float4*)s;
  const float4 b = *(const float4*)(s + 4);
  uint4 o;
  o.x = pack2h(a.x, a.y); o.y = pack2h(a.z, a.w);
  o.z = pack2h(b.x, b.y); o.w = pack2h(b.z, b.w);
  return o;
}
__device__ __forceinline__ int sd4(unsigned a, unsigned b, int acc) {
  return __builtin_amdgcn_sdot4((int)a, (int)b, acc, false);
}
__device__ __forceinline__ void dslice(const uint4 w, const unsigned* hq,
                                       int p, int& acc) {
  acc = sd4(w.x, hq[4 * p + 0], acc);
  acc = sd4(w.y, hq[4 * p + 1], acc);
  acc = sd4(w.z, hq[4 * p + 2], acc);
  acc = sd4(w.w, hq[4 * p + 3], acc);
}

#define DECL_OPQ(v, ptr, s)                                          \
  uint4 v = (ptr)[(s) * kH];                                         \
  asm volatile("" : "+v"(v.x), "+v"(v.y), "+v"(v.z), "+v"(v.w))

// ---- pre-pack: i8 recurrent (per-row scale) + f16 x-part + scales ----
__global__ void quant_weights(const float* __restrict__ Wz,
                              const float* __restrict__ Wr,
                              const float* __restrict__ Wg,
                              void* __restrict__ ws) {
  const int bx = blockIdx.x;            // 0..1535 = gate*512 + j
  const int gate = bx >> 9, j = bx & 511;
  const float* W = (gate == 0) ? Wz : (gate == 1) ? Wr : Wg;
  const float* row = W + (size_t)j * kFH;
  const int lane = threadIdx.x;         // 0..63, owns recurrent cols 8l..8l+7
  uint4* ws4 = (uint4*)ws;

  const float* src = row + kF + lane * 8;
  float v[8]; float m = 0.f;
#pragma unroll
  for (int i = 0; i < 8; ++i) { v[i] = src[i]; m = fmaxf(m, fabsf(v[i])); }
#pragma unroll
  for (int off = 32; off; off >>= 1) m = fmaxf(m, __shfl_xor(m, off));
  const float inv = 127.f / m;
  unsigned u0 = 0, u1 = 0;
#pragma unroll
  for (int i = 0; i < 4; ++i) {
    int q = __float2int_rn(v[i] * inv); q = max(-127, min(127, q));
    u0 |= ((unsigned)(q & 255)) << (8 * i);
  }
#pragma unroll
  for (int i = 0; i < 4; ++i) {
    int q = __float2int_rn(v[4 + i] * inv); q = max(-127, min(127, q));
    u1 |= ((unsigned)(q & 255)) << (8 * i);
  }
  const int p = lane >> 1, sub = lane & 1;
  const int qbase = (gate == 0) ? QZ4 : (gate == 1) ? QR4 : QG4;
  *(uint2*)((char*)ws + ((size_t)(qbase + p * kH + j)) * 16 + sub * 8) =
      make_uint2(u0, u1);
  if (lane < 16) {
    const int xbase = (gate == 0) ? WXZ4 : (gate == 1) ? WXR4 : WXG4;
    ws4[xbase + lane * kH + j] = pk8(row + lane * 8);
  }
  if (lane == 0)
    ((float*)((char*)ws + CS_OFF))[gate * 512 + j] = m / (127.f * HSCL);
}

// ---- x-part precompute: ax[b][t][gate][j] = b_gate[j] + Wx_gate[j].x_t ----
__global__ __launch_bounds__(512) void xpart_pre(
    const float* __restrict__ x, const float* __restrict__ bz,
    const float* __restrict__ br, const float* __restrict__ bg,
    const uint4* __restrict__ ws, unsigned short* __restrict__ axp) {
  __shared__ unsigned xt[8][64];        // 8 timesteps x 128 f16
  const int bx = blockIdx.x;            // 0..8191
  const int b = bx >> 6;
  const int t0 = (bx & 63) * 8;
  const int tid = threadIdx.x;          // 0..511 = j
  {
    const int m = tid >> 6, c = tid & 63;
    const float2 xv =
        *(const float2*)(x + ((size_t)b * kT + t0 + m) * kF + 2 * c);
    xt[m][c] = pack2h(xv.x, xv.y);
  }
  __syncthreads();
#pragma unroll
  for (int gate = 0; gate < 3; ++gate) {
    const uint4* wx =
        ws + ((gate == 0) ? WXZ4 : (gate == 1) ? WXR4 : WXG4) + tid;
    const float bv = ((gate == 0) ? bz : (gate == 1) ? br : bg)[tid];
    float acc[8];
#pragma unroll
    for (int m = 0; m < 8; ++m) acc[m] = bv;
#pragma unroll
    for (int p = 0; p < 16; ++p) {
      const uint4 w = wx[p * kH];
#pragma unroll
      for (int m = 0; m < 8; ++m)
        acc[m] = dot2x4(w, ((const uint4*)xt[m])[p], acc[m]);
    }
#pragma unroll
    for (int m = 0; m < 8; ++m)
      axp[(((size_t)b * kT + t0 + m) * 3 + gate) * kH + tid] = f2h(acc[m]);
  }
}

template <int XPRE>
__global__ __launch_bounds__(1024, 4) void cgru_i8s(
    const float* __restrict__ x, const float* __restrict__ td,
    const float* __restrict__ bz, const float* __restrict__ br,
    const float* __restrict__ bg, const uint4* __restrict__ ws,
    const unsigned short* __restrict__ axp, float* __restrict__ out) {
  __shared__ uint4 WLa[2][6][kH];      // z|r slices 8..13      98,304 B
  __shared__ uint4 WLg[2][3][kH];      // g slices {0..2|16..18} 49,152 B
  __shared__ unsigned hq[kH / 4];      // h, i8 plane
  __shared__ unsigned rq[kH / 4];      // r*h, i8 plane
  __shared__ unsigned xpk[kF / 2];     // x_t f16-packed (fallback mode only)
  __shared__ float gpart[kH];          // half1's g partial

  const int b = blockIdx.x;
  const int tid = threadIdx.x;
  const int j = tid & (kH - 1);
  const int half = tid >> 9;

  const uint4* __restrict__ wQa = ws + (half ? QR4 : QZ4) + j;
  const uint4* __restrict__ wQg = ws + QG4 + j;
  const uint4* __restrict__ wxa = ws + (half ? WXR4 : WXZ4) + j;
  const uint4* __restrict__ wxg = ws + WXG4 + j;
  const float* cs = (const float*)((const char*)ws + CS_OFF);
  const float csa = cs[(half ? 512 : 0) + j];
  const float csg = cs[1024 + j];

  // ---- reg-resident A-gate slices 0..7 (asm-opaque; fits 64-VGPR budget) ----
  DECL_OPQ(a0, wQa, 0); DECL_OPQ(a1, wQa, 1); DECL_OPQ(a2, wQa, 2);
  DECL_OPQ(a3, wQa, 3); DECL_OPQ(a4, wQa, 4); DECL_OPQ(a5, wQa, 5);
  DECL_OPQ(a6, wQa, 6); DECL_OPQ(a7, wQa, 7);
  // ---- LDS-resident slices ----
  {
    const uint4* qa = ws + (half ? QR4 : QZ4);
#pragma unroll
    for (int q = 0; q < 6; ++q) WLa[half][q][j] = qa[(8 + q) * kH + j];
#pragma unroll
    for (int q = 0; q < 3; ++q)
      WLg[half][q][j] = (ws + QG4)[((half ? 16 : 0) + q) * kH + j];
  }

  const float ba = half ? br[j] : bz[j];
  const float bgv = bg[j];
  float hb = 0.f, hs = 0.f, kacc = 0.f, zv = 0.f, dtv = 0.f;
  if (tid < kH / 4) hq[tid] = 0;       // h = 0
  if constexpr (XPRE) __syncthreads(); // hq init + LDS weights visible

  for (int t = 0; t < kT; ++t) {
    float ax, agx;
    if constexpr (XPRE) {
      // precomputed x-parts: gate index for the A-part == half (0:z, 1:r)
      const size_t bt3 = ((size_t)b * kT + t) * 3;
      ax = h2f(axp[(bt3 + half) * kH + j]);
      agx = half ? 0.f : h2f(axp[(bt3 + 2) * kH + j]);
      if (half == 0) dtv = fminf(td[(size_t)b * kT + t], 1.0f) * 0.5f;
    } else {
      if (tid < kF / 2) {   // stage x_t f16-packed
        const float2 xv =
            *(const float2*)(x + ((size_t)b * kT + t) * kF + 2 * tid);
        xpk[tid] = pack2h(xv.x, xv.y);
      }
      __syncthreads();      // xpk (+ init h, + LDS weights on t=0) visible
      const uint4* xp4 = (const uint4*)xpk;
      ax = ba;
#pragma unroll 4
      for (int p = 0; p < 16; ++p) ax = dot2x4(wxa[p * kH], xp4[p], ax);
      agx = half ? 0.f : bgv;
#pragma unroll 4
      for (int p = 0; p < 8; ++p)
        agx = dot2x4(wxg[(half * 8 + p) * kH], xp4[half * 8 + p], agx);
      if (half == 0) dtv = fminf(td[(size_t)b * kT + t], 1.0f) * 0.5f;
    }

    for (int e = 0; e < 8; ++e) {   // 2 ODE steps x 4 RK4 stages
      const int s = e & 3;
      // ---- A dot (z or r): 8 reg + 6 LDS + 18 streamed slices ----
      int ah = 0;
      dslice(a0, hq, 0, ah); dslice(a1, hq, 1, ah);
      dslice(a2, hq, 2, ah); dslice(a3, hq, 3, ah);
      dslice(a4, hq, 4, ah); dslice(a5, hq, 5, ah);
      dslice(a6, hq, 6, ah); dslice(a7, hq, 7, ah);
#pragma unroll
      for (int q = 0; q < 6; ++q)
        dslice(WLa[half][q][j], hq, 8 + q, ah);
#pragma unroll 6
      for (int p = 14; p < 32; ++p)
        dslice(wQa[p * kH], hq, p, ah);
      const float aA = ax + csa * (float)ah;

      if (half == 0) {
        zv = 1.0f / (1.0f + __expf(-aA));
      } else {
        const float r = 1.0f / (1.0f + __expf(-aA));
        const float hv = (float)((const char*)hq)[j] * (1.0f / HSCL);
        int q = __float2int_rn(fminf(fmaxf(r * hv, -1.27f), 1.27f) * HSCL);
        ((char*)rq)[j] = (char)q;
      }
      __syncthreads();   // #1: rh visible; h reads done

      // ---- G dot over rh: 3 LDS + 13 streamed (own K-half) ----
      int gh = 0;
      const int bs = half << 4;
#pragma unroll
      for (int q = 0; q < 3; ++q)
        dslice(WLg[half][q][j], rq, bs + q, gh);
#pragma unroll 4
      for (int p = bs + 3; p < bs + 16; ++p)
        dslice(wQg[p * kH], rq, p, gh);
      const float gp = agx + csg * (float)gh;
      if (half == 1) gpart[j] = gp;
      __syncthreads();   // #2: gpart visible; rh reads done

      if (half == 0) {
        const float g = tanhf(gp + gpart[j]);
        const float kk = (1.0f - zv) * (g - hs);
        kacc = (s == 0) ? kk : kacc + ((s == 3) ? 1.0f : 2.0f) * kk;
        float nxt;
        if (s < 3) {
          nxt = fmaf((s == 2 ? 1.0f : 0.5f) * dtv, kk, hb);
        } else {
          hb = fmaf(dtv * (1.0f / 6.0f), kacc, hb);
          nxt = hb;
        }
        hs = nxt;
        int q = __float2int_rn(fminf(fmaxf(nxt, -1.27f), 1.27f) * HSCL);
        ((char*)hq)[j] = (char)q;
      }
      __syncthreads();   // #3: new h visible
    }

    if (half == 0) out[((size_t)b * kT + t) * kH + j] = hb;  // coalesced
  }
}

extern "C" void kernel_launch(void* const* d_in, const int* in_sizes, int n_in,
                              void* d_out, int out_size, void* d_ws, size_t ws_size,
                              hipStream_t stream) {
  const float* x  = (const float*)d_in[0];
  const float* td = (const float*)d_in[1];
  const float* Wz = (const float*)d_in[2];
  const float* bz = (const float*)d_in[3];
  const float* Wr = (const float*)d_in[4];
  const float* br = (const float*)d_in[5];
  const float* Wg = (const float*)d_in[6];
  const float* bg = (const float*)d_in[7];
  float* out = (float*)d_out;

  quant_weights<<<3 * kH, 64, 0, stream>>>(Wz, Wr, Wg, d_ws);

  unsigned short* axp = (unsigned short*)((char*)d_ws + AXP_OFF);
  if (ws_size >= AXP_OFF + AXP_BYTES) {
    xpart_pre<<<kB * (kT / 8), 512, 0, stream>>>(
        x, bz, br, bg, (const uint4*)d_ws, axp);
    cgru_i8s<1><<<kB, 1024, 0, stream>>>(
        x, td, bz, br, bg, (const uint4*)d_ws, axp, out);
  } else {
    cgru_i8s<0><<<kB, 1024, 0, stream>>>(
        x, td, bz, br, bg, (const uint4*)d_ws, axp, out);
  }
}